// Round 11
// baseline (396.296 us; speedup 1.0000x reference)
//
#include <hip/hip_runtime.h>

#define N_NODES 50000
#define N_EDGES 1600000
#define IN_DIM 512
#define OUT_DIM 256

#define BK 32

// ---- two-level counting sort geometry (round-8 verified config) ----
#define RPB   128              // rows per bucket (rloc = 7 bits)
#define NBKT  391              // ceil(50000 / 128)
#define CHUNK 4096             // edges per scatter1 block (4096 verified; 2048 regressed)
#define EPT   16               // edges per thread in scatter1
#define CAP   5120             // per-bucket tmp capacity (mean 4096, sigma 64 -> +16 sigma)

typedef unsigned int u32;
typedef unsigned short u16;
typedef short bf16x8 __attribute__((ext_vector_type(8)));
typedef float f32x4 __attribute__((ext_vector_type(4)));

__device__ __forceinline__ float bf_to_f(u16 u) { return __uint_as_float(((u32)u) << 16); }
__device__ __forceinline__ u16 f_to_bf(float f) {
    u32 u = __float_as_uint(f);
    u32 r = (u + 0x7fffu + ((u >> 16) & 1u)) >> 16;   // RNE
    return (u16)r;
}

__device__ __forceinline__ bf16x8 cvt8(float4 a, float4 b) {
    bf16x8 r;
    r[0] = (short)f_to_bf(a.x); r[1] = (short)f_to_bf(a.y);
    r[2] = (short)f_to_bf(a.z); r[3] = (short)f_to_bf(a.w);
    r[4] = (short)f_to_bf(b.x); r[5] = (short)f_to_bf(b.y);
    r[6] = (short)f_to_bf(b.z); r[7] = (short)f_to_bf(b.w);
    return r;
}

// ---------------------------------------------------------------------------
// CSR build, two-level (round-8 verified: CHUNK=4096).
// ---------------------------------------------------------------------------
__global__ __launch_bounds__(256) void scatter1(const int* __restrict__ er,
                                                const int* __restrict__ ec,
                                                const float* __restrict__ ev,
                                                int* __restrict__ cursor,
                                                int2* __restrict__ tmp) {
    __shared__ int  hcnt[NBKT];
    __shared__ int  loff[NBKT];
    __shared__ int  gbase[NBKT];
    __shared__ int  sc[512];
    __shared__ int2 estage[CHUNK];   // 32 KB
    __shared__ u16  bslot[CHUNK];    //  8 KB

    const int t = threadIdx.x;
    const int base = blockIdx.x * CHUNK;
    const int nedge = min(CHUNK, N_EDGES - base);

    for (int k = t; k < NBKT; k += 256) hcnt[k] = 0;
    __syncthreads();

    int w0[EPT], w1[EPT], rk[EPT];
    #pragma unroll
    for (int j = 0; j < EPT; ++j) {
        const int i = j * 256 + t;            // coalesced per j
        rk[j] = -1;
        if (i < nedge) {
            const int e = base + i;
            const int r = er[e];
            const int bk = r >> 7;
            w0[j] = ec[e] | ((r & 127) << 16) | (bk << 23);
            w1[j] = __float_as_int(ev[e]);
            rk[j] = atomicAdd(&hcnt[bk], 1);
        }
    }
    __syncthreads();

    sc[t]       = (t < NBKT) ? hcnt[t] : 0;
    sc[t + 256] = (t + 256 < NBKT) ? hcnt[t + 256] : 0;
    __syncthreads();
    #pragma unroll
    for (int off = 1; off < 512; off <<= 1) {
        const int a0 = (t >= off) ? sc[t - off] : 0;
        const int a1 = sc[t + 256 - off];
        __syncthreads();
        sc[t] += a0;
        sc[t + 256] += a1;
        __syncthreads();
    }
    if (t < NBKT)       loff[t]       = sc[t] - hcnt[t];
    if (t + 256 < NBKT) loff[t + 256] = sc[t + 256] - hcnt[t + 256];

    if (t < NBKT && hcnt[t] > 0)
        gbase[t] = t * CAP + atomicAdd(&cursor[t], hcnt[t]);
    if (t + 256 < NBKT && hcnt[t + 256] > 0)
        gbase[t + 256] = (t + 256) * CAP + atomicAdd(&cursor[t + 256], hcnt[t + 256]);
    __syncthreads();

    #pragma unroll
    for (int j = 0; j < EPT; ++j) {
        if (rk[j] >= 0) {
            const int bk = ((u32)w0[j]) >> 23;
            const int s = loff[bk] + rk[j];
            estage[s] = make_int2(w0[j], w1[j]);
            bslot[s]  = (u16)bk;
        }
    }
    __syncthreads();

    for (int s = t; s < nedge; s += 256) {
        const int bk = bslot[s];
        const int2 e2 = estage[s];
        const int gpos = gbase[bk] + (s - loff[bk]);
        if (gpos < (bk + 1) * CAP)            // overflow guard (never in practice)
            tmp[gpos] = e2;
    }
}

// per bucket: inline 391-scan of bucket counts, then LDS row-hist + scan ->
// row_ptr, scatter into 32KB L2-resident window with LDS cursors.
__global__ __launch_bounds__(256) void scatter2(const int* __restrict__ cursor,
                                                const int2* __restrict__ tmp,
                                                int* __restrict__ row_ptr,
                                                int2* __restrict__ sedge) {
    __shared__ int sc[512];
    __shared__ int orig[512];
    __shared__ int rcnt[RPB];
    __shared__ int rsc[RPB];
    __shared__ int rcur[RPB];
    const int t = threadIdx.x;
    const int b = blockIdx.x;

    const int c0 = (t < NBKT) ? min(cursor[t], CAP) : 0;
    const int c1 = (t + 256 < NBKT) ? min(cursor[t + 256], CAP) : 0;
    sc[t] = c0;       orig[t] = c0;
    sc[t + 256] = c1; orig[t + 256] = c1;
    __syncthreads();
    #pragma unroll
    for (int off = 1; off < 512; off <<= 1) {
        const int a0 = (t >= off) ? sc[t - off] : 0;
        const int a1 = sc[t + 256 - off];
        __syncthreads();
        sc[t] += a0;
        sc[t + 256] += a1;
        __syncthreads();
    }
    const int gb = sc[b] - orig[b];           // exclusive prefix at bucket b
    const int n  = orig[b];                   // this bucket's edge count
    const int2* src = tmp + (size_t)b * CAP;

    if (b == 0 && t == 0) row_ptr[N_NODES] = N_EDGES;

    if (t < RPB) rcnt[t] = 0;
    __syncthreads();
    for (int i = t; i < n; i += 256)
        atomicAdd(&rcnt[(((u32)src[i].x) >> 16) & 127], 1);
    __syncthreads();

    if (t < RPB) rsc[t] = rcnt[t];
    __syncthreads();
    #pragma unroll
    for (int off = 1; off < RPB; off <<= 1) {
        int a = 0;
        if (t < RPB && t >= off) a = rsc[t - off];
        __syncthreads();
        if (t < RPB) rsc[t] += a;
        __syncthreads();
    }
    if (t < RPB) {
        const int excl = rsc[t] - rcnt[t];
        rcur[t] = gb + excl;
        const int row = b * RPB + t;
        if (row < N_NODES) row_ptr[row] = gb + excl;
    }
    __syncthreads();

    for (int i = t; i < n; i += 256) {
        const int2 e2 = src[i];                       // L2-hot (2nd pass)
        const int rloc = (((u32)e2.x) >> 16) & 127;
        const int pos = atomicAdd(&rcur[rloc], 1);    // LDS atomic
        sedge[pos] = make_int2(e2.x & 0xFFFF, e2.y);  // within 32KB window
    }
}

// ---------------------------------------------------------------------------
// W [512,256] fp32 -> WT [256,512] bf16 (transposed); also zeroes cursor[].
// ---------------------------------------------------------------------------
__global__ __launch_bounds__(256) void wcvt_zero(const float* __restrict__ W,
                                                 u16* __restrict__ WT,
                                                 int* __restrict__ cursor) {
    if (blockIdx.x < 2) {
        const int i = blockIdx.x * 256 + threadIdx.x;
        if (i < NBKT) cursor[i] = 0;
    }
    const int n  = threadIdx.x;
    const int k0 = blockIdx.x * 4;
    ushort4 o;
    o.x = f_to_bf(W[(size_t)(k0 + 0) * OUT_DIM + n]);
    o.y = f_to_bf(W[(size_t)(k0 + 1) * OUT_DIM + n]);
    o.z = f_to_bf(W[(size_t)(k0 + 2) * OUT_DIM + n]);
    o.w = f_to_bf(W[(size_t)(k0 + 3) * OUT_DIM + n]);
    *(ushort4*)(WT + (size_t)n * IN_DIM + k0) = o;
}

// ---------------------------------------------------------------------------
// gemm_direct: Sb[M,256] = bf16( X @ W ), MFMA 16x16x32, NO LDS, NO BARRIERS.
// Rounds 8-9 showed the staged GEMM is barrier-latency bound (MfmaUtil 6-8%,
// occupancy fix regressed: +2x B-staging + LDS conflicts).  Here each lane
// loads its MFMA fragments straight from global: A = 2x float4 of X (row
// l15, k quad*8; converted in-register), B = one 16B load of WT which IS the
// fragment ([col][k] layout, L2-resident 256KB, L1-shared within block).
// K-loop = independent loads + MFMAs only -> wave-parallelism hides latency.
// Wave = 32 rows x 128 cols; block = 4 waves = 128 rows; grid = 391*2.
// X read 2x (col-halves) but X = 102MB < L3 -> second read L3-served.
// ---------------------------------------------------------------------------
__global__ __launch_bounds__(256) void gemm_direct(const float* __restrict__ X,
                                                   const u16* __restrict__ WT,
                                                   u16* __restrict__ Sb) {
    const int tid  = threadIdx.x;
    const int wave = tid >> 6;
    const int lane = tid & 63;
    const int l15  = lane & 15;
    const int quad = lane >> 4;
    const int rw   = (blockIdx.x >> 1) * 128 + wave * 32;   // wave row base
    const int c0   = (blockIdx.x & 1) * 128;                // wave col base

    const float* xa0 = X + (size_t)min(rw + l15,      N_NODES - 1) * IN_DIM + quad * 8;
    const float* xa1 = X + (size_t)min(rw + 16 + l15, N_NODES - 1) * IN_DIM + quad * 8;
    const u16*   wb  = WT + (size_t)(c0 + l15) * IN_DIM + quad * 8;

    f32x4 acc[2][8];
    #pragma unroll
    for (int i = 0; i < 2; ++i)
        #pragma unroll
        for (int j = 0; j < 8; ++j) acc[i][j] = (f32x4)0.f;

    #pragma unroll 2
    for (int kc = 0; kc < IN_DIM; kc += BK) {
        const float4 a00 = *(const float4*)(xa0 + kc);
        const float4 a01 = *(const float4*)(xa0 + kc + 4);
        const float4 a10 = *(const float4*)(xa1 + kc);
        const float4 a11 = *(const float4*)(xa1 + kc + 4);
        bf16x8 bfr[8];
        #pragma unroll
        for (int nt = 0; nt < 8; ++nt)
            bfr[nt] = *(const bf16x8*)(wb + (size_t)nt * 16 * IN_DIM + kc);
        const bf16x8 af0 = cvt8(a00, a01);
        const bf16x8 af1 = cvt8(a10, a11);
        #pragma unroll
        for (int nt = 0; nt < 8; ++nt) {
            acc[0][nt] = __builtin_amdgcn_mfma_f32_16x16x32_bf16(af0, bfr[nt], acc[0][nt], 0, 0, 0);
            acc[1][nt] = __builtin_amdgcn_mfma_f32_16x16x32_bf16(af1, bfr[nt], acc[1][nt], 0, 0, 0);
        }
    }

    // epilogue: D[row = quad*4 + rr][col = l15] per 16x16 tile; Sb row-major
    #pragma unroll
    for (int mt = 0; mt < 2; ++mt) {
        #pragma unroll
        for (int rr = 0; rr < 4; ++rr) {
            const int grow = rw + mt * 16 + quad * 4 + rr;
            if (grow < N_NODES) {
                u16* dst = Sb + (size_t)grow * OUT_DIM + c0 + l15;
                #pragma unroll
                for (int nt = 0; nt < 8; ++nt)
                    dst[nt * 16] = f_to_bf(acc[mt][nt][rr]);
            }
        }
    }
}

// ---------------------------------------------------------------------------
// out[r] = bias + sum_{e in row r} val[e] * Sb[col[e]]  (round-7 form)
// Split into two half-row launches: keeps the rocprof top-5 cutoff low so
// remainder kernels stay visible.
// ---------------------------------------------------------------------------
__global__ __launch_bounds__(256) void csr_spmm(const int* __restrict__ row_ptr,
                                                const int2* __restrict__ sedge,
                                                const u16* __restrict__ Sb,
                                                const float* __restrict__ bias,
                                                float* __restrict__ out,
                                                int rbase) {
    const int wave = threadIdx.x >> 6;
    const int lane = threadIdx.x & 63;
    const int r = rbase + blockIdx.x * 4 + wave;
    if (r >= N_NODES) return;

    const int start = row_ptr[r];
    const int end   = row_ptr[r + 1];

    float4 acc = *(const float4*)(bias + lane * 4);
    const u16* sbase = Sb + lane * 4;

    int e = start;
    for (; e + 16 <= end; e += 16) {
        int2 ed[16];
        #pragma unroll
        for (int j = 0; j < 16; ++j) ed[j] = sedge[e + j];

        ushort4 sv[16];
        #pragma unroll
        for (int j = 0; j < 16; ++j)
            sv[j] = *(const ushort4*)(sbase + (size_t)ed[j].x * OUT_DIM);

        #pragma unroll
        for (int j = 0; j < 16; ++j) {
            const float vj = __int_as_float(ed[j].y);
            acc.x += vj * bf_to_f(sv[j].x);
            acc.y += vj * bf_to_f(sv[j].y);
            acc.z += vj * bf_to_f(sv[j].z);
            acc.w += vj * bf_to_f(sv[j].w);
        }
    }
    if (e < end) {
        int2 ed[16];
        #pragma unroll
        for (int j = 0; j < 16; ++j)
            ed[j] = sedge[min(e + j, end - 1)];
        #pragma unroll
        for (int j = 0; j < 16; ++j)
            if (e + j >= end) ed[j].y = 0;            // 0.0f bits on padding

        ushort4 sv[16];
        #pragma unroll
        for (int j = 0; j < 16; ++j)
            sv[j] = *(const ushort4*)(sbase + (size_t)ed[j].x * OUT_DIM);

        #pragma unroll
        for (int j = 0; j < 16; ++j) {
            const float vj = __int_as_float(ed[j].y);
            acc.x += vj * bf_to_f(sv[j].x);
            acc.y += vj * bf_to_f(sv[j].y);
            acc.z += vj * bf_to_f(sv[j].z);
            acc.w += vj * bf_to_f(sv[j].w);
        }
    }

    *(float4*)(out + (size_t)r * OUT_DIM + lane * 4) = acc;
}

extern "C" void kernel_launch(void* const* d_in, const int* in_sizes, int n_in,
                              void* d_out, int out_size, void* d_ws, size_t ws_size,
                              hipStream_t stream) {
    const float* X    = (const float*)d_in[0];
    const int*   er   = (const int*)d_in[1];
    const int*   ec   = (const int*)d_in[2];
    const float* ev   = (const float*)d_in[3];
    const float* W    = (const float*)d_in[4];
    const float* bias = (const float*)d_in[5];
    float* out        = (float*)d_out;

    // ws layout (~38.9 MB).  tmp/cursor alias the Sb region: they are dead
    // before gemm_direct writes Sb (stream-ordered).
    char* ws = (char*)d_ws;
    u16*  Sb      = (u16*) (ws);                       // 25,600,000 B
    int2* tmp     = (int2*)(ws);                       // 16,015,360 B (alias)
    int*  cursor  = (int*) (ws + 16100000);            //      1,564 B (alias)
    int2* sedge   = (int2*)(ws + 25600000);            // 12,800,000 B
    u16*  WT      = (u16*) (ws + 38400000);            //    262,144 B
    int*  row_ptr = (int*) (ws + 38662144);            //    200,004 B

    hipLaunchKernelGGL(wcvt_zero, dim3(IN_DIM / 4), dim3(256), 0, stream,
                       W, WT, cursor);
    hipLaunchKernelGGL(scatter1, dim3((N_EDGES + CHUNK - 1) / CHUNK), dim3(256), 0,
                       stream, er, ec, ev, cursor, tmp);
    hipLaunchKernelGGL(scatter2, dim3(NBKT), dim3(256), 0, stream,
                       cursor, tmp, row_ptr, sedge);
    hipLaunchKernelGGL(gemm_direct, dim3(2 * ((N_NODES + 127) / 128)), dim3(256), 0,
                       stream, X, WT, Sb);
    hipLaunchKernelGGL(csr_spmm, dim3(25000 / 4), dim3(256), 0, stream,
                       row_ptr, sedge, Sb, bias, out, 0);
    hipLaunchKernelGGL(csr_spmm, dim3(25000 / 4), dim3(256), 0, stream,
                       row_ptr, sedge, Sb, bias, out, 25000);
}

// Round 12
// 360.518 us; speedup vs baseline: 1.0992x; 1.0992x over previous
//
#include <hip/hip_runtime.h>

#define N_NODES 50000
#define N_EDGES 1600000
#define IN_DIM 512
#define OUT_DIM 256

#define BM 64                  // round-8 verified gemm geometry (64.6us)
#define BN 256
#define BK 32
#define APAD 8
#define LDA (BK + APAD)

// ---- two-level counting sort geometry (round-8 verified config) ----
#define RPB   128
#define NBKT  391
#define CHUNK 4096
#define EPT   16
#define CAP   5120

typedef unsigned int u32;
typedef unsigned short u16;
typedef short bf16x8 __attribute__((ext_vector_type(8)));
typedef float f32x4 __attribute__((ext_vector_type(4)));

__device__ __forceinline__ float bf_to_f(u16 u) { return __uint_as_float(((u32)u) << 16); }
__device__ __forceinline__ u16 f_to_bf(float f) {
    u32 u = __float_as_uint(f);
    u32 r = (u + 0x7fffu + ((u >> 16) & 1u)) >> 16;   // RNE
    return (u16)r;
}

// ---------------------------------------------------------------------------
// scatter1: edges -> bucket-major tmp (round-8 verified).
// ---------------------------------------------------------------------------
__global__ __launch_bounds__(256) void scatter1(const int* __restrict__ er,
                                                const int* __restrict__ ec,
                                                const float* __restrict__ ev,
                                                int* __restrict__ cursor,
                                                int2* __restrict__ tmp) {
    __shared__ int  hcnt[NBKT];
    __shared__ int  loff[NBKT];
    __shared__ int  gbase[NBKT];
    __shared__ int  sc[512];
    __shared__ int2 estage[CHUNK];   // 32 KB
    __shared__ u16  bslot[CHUNK];    //  8 KB

    const int t = threadIdx.x;
    const int base = blockIdx.x * CHUNK;
    const int nedge = min(CHUNK, N_EDGES - base);

    for (int k = t; k < NBKT; k += 256) hcnt[k] = 0;
    __syncthreads();

    int w0[EPT], w1[EPT], rk[EPT];
    #pragma unroll
    for (int j = 0; j < EPT; ++j) {
        const int i = j * 256 + t;            // coalesced per j
        rk[j] = -1;
        if (i < nedge) {
            const int e = base + i;
            const int r = er[e];
            const int bk = r >> 7;
            w0[j] = ec[e] | ((r & 127) << 16) | (bk << 23);
            w1[j] = __float_as_int(ev[e]);
            rk[j] = atomicAdd(&hcnt[bk], 1);
        }
    }
    __syncthreads();

    sc[t]       = (t < NBKT) ? hcnt[t] : 0;
    sc[t + 256] = (t + 256 < NBKT) ? hcnt[t + 256] : 0;
    __syncthreads();
    #pragma unroll
    for (int off = 1; off < 512; off <<= 1) {
        const int a0 = (t >= off) ? sc[t - off] : 0;
        const int a1 = sc[t + 256 - off];
        __syncthreads();
        sc[t] += a0;
        sc[t + 256] += a1;
        __syncthreads();
    }
    if (t < NBKT)       loff[t]       = sc[t] - hcnt[t];
    if (t + 256 < NBKT) loff[t + 256] = sc[t + 256] - hcnt[t + 256];

    if (t < NBKT && hcnt[t] > 0)
        gbase[t] = t * CAP + atomicAdd(&cursor[t], hcnt[t]);
    if (t + 256 < NBKT && hcnt[t + 256] > 0)
        gbase[t + 256] = (t + 256) * CAP + atomicAdd(&cursor[t + 256], hcnt[t + 256]);
    __syncthreads();

    #pragma unroll
    for (int j = 0; j < EPT; ++j) {
        if (rk[j] >= 0) {
            const int bk = ((u32)w0[j]) >> 23;
            const int s = loff[bk] + rk[j];
            estage[s] = make_int2(w0[j], w1[j]);
            bslot[s]  = (u16)bk;
        }
    }
    __syncthreads();

    for (int s = t; s < nedge; s += 256) {
        const int bk = bslot[s];
        const int2 e2 = estage[s];
        const int gpos = gbase[bk] + (s - loff[bk]);
        if (gpos < (bk + 1) * CAP)            // overflow guard (never in practice)
            tmp[gpos] = e2;
    }
}

// ---------------------------------------------------------------------------
// W [512,256] fp32 -> WT [256,512] bf16 (transposed); also zeroes cursor[].
// ---------------------------------------------------------------------------
__global__ __launch_bounds__(256) void wcvt_zero(const float* __restrict__ W,
                                                 u16* __restrict__ WT,
                                                 int* __restrict__ cursor) {
    if (blockIdx.x < 2) {
        const int i = blockIdx.x * 256 + threadIdx.x;
        if (i < NBKT) cursor[i] = 0;
    }
    const int n  = threadIdx.x;
    const int k0 = blockIdx.x * 4;
    ushort4 o;
    o.x = f_to_bf(W[(size_t)(k0 + 0) * OUT_DIM + n]);
    o.y = f_to_bf(W[(size_t)(k0 + 1) * OUT_DIM + n]);
    o.z = f_to_bf(W[(size_t)(k0 + 2) * OUT_DIM + n]);
    o.w = f_to_bf(W[(size_t)(k0 + 3) * OUT_DIM + n]);
    *(ushort4*)(WT + (size_t)n * IN_DIM + k0) = o;
}

// ---------------------------------------------------------------------------
// FUSED heterogeneous kernel: blocks [0, NBKT) run scatter2; blocks
// [NBKT, NBKT+782) run the round-8-verified gemm (BM=64/BN=256, reg
// prefetch).  The two sub-grids have NO data dependency (gemm needs only
// WT; scatter2 needs scatter1's tmp) and stress different pipes
// (LDS-atomic/latency vs MFMA/HBM) -> co-residency overlaps the previously
// SERIAL ~60us + ~65us into ~max().  All 1173 blocks fit on-chip
// (256 CU x 6 blocks/CU at 25.6KB LDS-union).  scatter2 blocks dispatch
// first (lower blockIdx) since they feed the spmm critical path.
// LDS is a 25.6KB union: gemm As(5120)+Bs(20480) | scatter2 arrays (5.6KB).
// ---------------------------------------------------------------------------
__global__ __launch_bounds__(256) void fused_s2_gemm(const int* __restrict__ cursor,
                                                     const int2* __restrict__ tmp,
                                                     int* __restrict__ row_ptr,
                                                     int2* __restrict__ sedge,
                                                     const float* __restrict__ X,
                                                     const u16* __restrict__ WT,
                                                     u16* __restrict__ Sb) {
    __shared__ __align__(16) char smem[BM * LDA * 2 + BN * LDA * 2];   // 25,600 B

    const int t = threadIdx.x;

    if (blockIdx.x < NBKT) {
        // ---------------- scatter2 role (verbatim round-8 logic) ----------
        int* sc   = (int*)smem;          // 512
        int* orig = sc + 512;            // 512
        int* rcnt = orig + 512;          // 128
        int* rsc  = rcnt + RPB;          // 128
        int* rcur = rsc + RPB;           // 128
        const int b = blockIdx.x;

        const int c0 = (t < NBKT) ? min(cursor[t], CAP) : 0;
        const int c1 = (t + 256 < NBKT) ? min(cursor[t + 256], CAP) : 0;
        sc[t] = c0;       orig[t] = c0;
        sc[t + 256] = c1; orig[t + 256] = c1;
        __syncthreads();
        #pragma unroll
        for (int off = 1; off < 512; off <<= 1) {
            const int a0 = (t >= off) ? sc[t - off] : 0;
            const int a1 = sc[t + 256 - off];
            __syncthreads();
            sc[t] += a0;
            sc[t + 256] += a1;
            __syncthreads();
        }
        const int gb = sc[b] - orig[b];           // exclusive prefix at bucket b
        const int n  = orig[b];                   // this bucket's edge count
        const int2* src = tmp + (size_t)b * CAP;

        if (b == 0 && t == 0) row_ptr[N_NODES] = N_EDGES;

        if (t < RPB) rcnt[t] = 0;
        __syncthreads();
        for (int i = t; i < n; i += 256)
            atomicAdd(&rcnt[(((u32)src[i].x) >> 16) & 127], 1);
        __syncthreads();

        if (t < RPB) rsc[t] = rcnt[t];
        __syncthreads();
        #pragma unroll
        for (int off = 1; off < RPB; off <<= 1) {
            int a = 0;
            if (t < RPB && t >= off) a = rsc[t - off];
            __syncthreads();
            if (t < RPB) rsc[t] += a;
            __syncthreads();
        }
        if (t < RPB) {
            const int excl = rsc[t] - rcnt[t];
            rcur[t] = gb + excl;
            const int row = b * RPB + t;
            if (row < N_NODES) row_ptr[row] = gb + excl;
        }
        __syncthreads();

        for (int i = t; i < n; i += 256) {
            const int2 e2 = src[i];                       // L2-hot (2nd pass)
            const int rloc = (((u32)e2.x) >> 16) & 127;
            const int pos = atomicAdd(&rcur[rloc], 1);    // LDS atomic
            sedge[pos] = make_int2(e2.x & 0xFFFF, e2.y);  // within 32KB window
        }
    } else {
        // ---------------- gemm role (verbatim round-8 logic, 64.6us) ------
        u16* As = (u16*)smem;                    // [BM][LDA]  5,120 B
        u16* Bs = (u16*)(smem + BM * LDA * 2);   // [BN][LDA] 20,480 B

        const int wave = t >> 6;
        const int lane = t & 63;
        const int r0   = (blockIdx.x - NBKT) * BM;
        const int wn   = wave * 64;
        const int l15  = lane & 15;
        const int quad = lane >> 4;

        f32x4 acc[4][4];
        #pragma unroll
        for (int i = 0; i < 4; ++i)
            #pragma unroll
            for (int j = 0; j < 4; ++j) acc[i][j] = (f32x4)0.f;

        const int arow = t >> 2;
        const int akp  = (t & 3) * 8;
        const int xrow = min(r0 + arow, N_NODES - 1);
        const float* xsrc = X + (size_t)xrow * IN_DIM + akp;
        const int brow = t >> 1;
        const int bkp  = (t & 1) * 16;
        const u16* bsrc  = WT + (size_t)brow * IN_DIM + bkp;
        const u16* bsrc2 = bsrc + (size_t)128 * IN_DIM;

        float4 fA0 = *(const float4*)(xsrc + 0);
        float4 fA1 = *(const float4*)(xsrc + 4);
        uint4  rB0 = *(const uint4*)(bsrc + 0);
        uint4  rB1 = *(const uint4*)(bsrc + 8);
        uint4  rB2 = *(const uint4*)(bsrc2 + 0);
        uint4  rB3 = *(const uint4*)(bsrc2 + 8);

        for (int kc = 0; kc < IN_DIM; kc += BK) {
            {
                ushort4 p0, p1;
                p0.x = f_to_bf(fA0.x); p0.y = f_to_bf(fA0.y); p0.z = f_to_bf(fA0.z); p0.w = f_to_bf(fA0.w);
                p1.x = f_to_bf(fA1.x); p1.y = f_to_bf(fA1.y); p1.z = f_to_bf(fA1.z); p1.w = f_to_bf(fA1.w);
                *(ushort4*)&As[arow * LDA + akp + 0] = p0;
                *(ushort4*)&As[arow * LDA + akp + 4] = p1;
                *(uint4*)&Bs[brow * LDA + bkp + 0] = rB0;
                *(uint4*)&Bs[brow * LDA + bkp + 8] = rB1;
                *(uint4*)&Bs[(brow + 128) * LDA + bkp + 0] = rB2;
                *(uint4*)&Bs[(brow + 128) * LDA + bkp + 8] = rB3;
            }
            __syncthreads();

            if (kc + BK < IN_DIM) {
                fA0 = *(const float4*)(xsrc + kc + BK + 0);
                fA1 = *(const float4*)(xsrc + kc + BK + 4);
                rB0 = *(const uint4*)(bsrc + kc + BK + 0);
                rB1 = *(const uint4*)(bsrc + kc + BK + 8);
                rB2 = *(const uint4*)(bsrc2 + kc + BK + 0);
                rB3 = *(const uint4*)(bsrc2 + kc + BK + 8);
            }

            bf16x8 af[4], bfr[4];
            #pragma unroll
            for (int mt = 0; mt < 4; ++mt)
                af[mt] = *(const bf16x8*)&As[(mt * 16 + l15) * LDA + quad * 8];
            #pragma unroll
            for (int nt = 0; nt < 4; ++nt)
                bfr[nt] = *(const bf16x8*)&Bs[(wn + nt * 16 + l15) * LDA + quad * 8];
            #pragma unroll
            for (int mt = 0; mt < 4; ++mt)
                #pragma unroll
                for (int nt = 0; nt < 4; ++nt)
                    acc[mt][nt] = __builtin_amdgcn_mfma_f32_16x16x32_bf16(
                        af[mt], bfr[nt], acc[mt][nt], 0, 0, 0);
            __syncthreads();
        }

        #pragma unroll
        for (int mt = 0; mt < 4; ++mt) {
            #pragma unroll
            for (int r = 0; r < 4; ++r) {
                const int grow = r0 + mt * 16 + quad * 4 + r;
                if (grow < N_NODES) {
                    u16* dst = Sb + (size_t)grow * OUT_DIM + wn + l15;
                    #pragma unroll
                    for (int nt = 0; nt < 4; ++nt)
                        dst[nt * 16] = f_to_bf(acc[mt][nt][r]);
                }
            }
        }
    }
}

// ---------------------------------------------------------------------------
// out[r] = bias + sum_{e in row r} val[e] * Sb[col[e]]  (round-7/8 form)
// Split into two half-row launches (keeps remainder kernels visible).
// ---------------------------------------------------------------------------
__global__ __launch_bounds__(256) void csr_spmm(const int* __restrict__ row_ptr,
                                                const int2* __restrict__ sedge,
                                                const u16* __restrict__ Sb,
                                                const float* __restrict__ bias,
                                                float* __restrict__ out,
                                                int rbase) {
    const int wave = threadIdx.x >> 6;
    const int lane = threadIdx.x & 63;
    const int r = rbase + blockIdx.x * 4 + wave;
    if (r >= N_NODES) return;

    const int start = row_ptr[r];
    const int end   = row_ptr[r + 1];

    float4 acc = *(const float4*)(bias + lane * 4);
    const u16* sbase = Sb + lane * 4;

    int e = start;
    for (; e + 16 <= end; e += 16) {
        int2 ed[16];
        #pragma unroll
        for (int j = 0; j < 16; ++j) ed[j] = sedge[e + j];

        ushort4 sv[16];
        #pragma unroll
        for (int j = 0; j < 16; ++j)
            sv[j] = *(const ushort4*)(sbase + (size_t)ed[j].x * OUT_DIM);

        #pragma unroll
        for (int j = 0; j < 16; ++j) {
            const float vj = __int_as_float(ed[j].y);
            acc.x += vj * bf_to_f(sv[j].x);
            acc.y += vj * bf_to_f(sv[j].y);
            acc.z += vj * bf_to_f(sv[j].z);
            acc.w += vj * bf_to_f(sv[j].w);
        }
    }
    if (e < end) {
        int2 ed[16];
        #pragma unroll
        for (int j = 0; j < 16; ++j)
            ed[j] = sedge[min(e + j, end - 1)];
        #pragma unroll
        for (int j = 0; j < 16; ++j)
            if (e + j >= end) ed[j].y = 0;            // 0.0f bits on padding

        ushort4 sv[16];
        #pragma unroll
        for (int j = 0; j < 16; ++j)
            sv[j] = *(const ushort4*)(sbase + (size_t)ed[j].x * OUT_DIM);

        #pragma unroll
        for (int j = 0; j < 16; ++j) {
            const float vj = __int_as_float(ed[j].y);
            acc.x += vj * bf_to_f(sv[j].x);
            acc.y += vj * bf_to_f(sv[j].y);
            acc.z += vj * bf_to_f(sv[j].z);
            acc.w += vj * bf_to_f(sv[j].w);
        }
    }

    *(float4*)(out + (size_t)r * OUT_DIM + lane * 4) = acc;
}

extern "C" void kernel_launch(void* const* d_in, const int* in_sizes, int n_in,
                              void* d_out, int out_size, void* d_ws, size_t ws_size,
                              hipStream_t stream) {
    const float* X    = (const float*)d_in[0];
    const int*   er   = (const int*)d_in[1];
    const int*   ec   = (const int*)d_in[2];
    const float* ev   = (const float*)d_in[3];
    const float* W    = (const float*)d_in[4];
    const float* bias = (const float*)d_in[5];
    float* out        = (float*)d_out;

    // ws layout (~38.9 MB).  tmp/cursor alias the Sb region: tmp is consumed
    // by scatter2 blocks while gemm blocks write Sb -- but the regions are
    // DISJOINT?  NO: tmp aliases Sb bytes [0, 16MB).  In the fused kernel
    // scatter2 reads tmp WHILE gemm writes Sb -> must NOT alias.  Move tmp
    // to its own region: Sb 25.6MB | sedge 12.8MB | tmp 16.1MB | rest.
    char* ws = (char*)d_ws;
    u16*  Sb      = (u16*) (ws);                       // 25,600,000 B
    int2* sedge   = (int2*)(ws + 25600000);            // 12,800,000 B
    int2* tmp     = (int2*)(ws + 38400000);            // 16,015,360 B
    u16*  WT      = (u16*) (ws + 54415360);            //    262,144 B
    int*  row_ptr = (int*) (ws + 54677504);            //    200,004 B
    int*  cursor  = (int*) (ws + 54877508);            //      1,564 B

    hipLaunchKernelGGL(wcvt_zero, dim3(IN_DIM / 4), dim3(256), 0, stream,
                       W, WT, cursor);
    hipLaunchKernelGGL(scatter1, dim3((N_EDGES + CHUNK - 1) / CHUNK), dim3(256), 0,
                       stream, er, ec, ev, cursor, tmp);
    hipLaunchKernelGGL(fused_s2_gemm, dim3(NBKT + (N_NODES + BM - 1) / BM),
                       dim3(256), 0, stream,
                       cursor, tmp, row_ptr, sedge, X, WT, Sb);
    hipLaunchKernelGGL(csr_spmm, dim3(25000 / 4), dim3(256), 0, stream,
                       row_ptr, sedge, Sb, bias, out, 0);
    hipLaunchKernelGGL(csr_spmm, dim3(25000 / 4), dim3(256), 0, stream,
                       row_ptr, sedge, Sb, bias, out, 25000);
}

// Round 13
// 348.561 us; speedup vs baseline: 1.1369x; 1.0343x over previous
//
#include <hip/hip_runtime.h>

#define N_NODES 50000
#define N_EDGES 1600000
#define IN_DIM 512
#define OUT_DIM 256

#define BM 64                  // round-8 verified gemm geometry (64.6us)
#define BN 256
#define BK 32
#define APAD 8
#define LDA (BK + APAD)

// ---- two-level counting sort geometry (round-8 verified config) ----
#define RPB   128
#define NBKT  391
#define CHUNK 4096
#define EPT   16
#define CAP   5120

typedef unsigned int u32;
typedef unsigned short u16;
typedef short bf16x8 __attribute__((ext_vector_type(8)));
typedef float f32x4 __attribute__((ext_vector_type(4)));

__device__ __forceinline__ float bf_to_f(u16 u) { return __uint_as_float(((u32)u) << 16); }
__device__ __forceinline__ u16 f_to_bf(float f) {
    u32 u = __float_as_uint(f);
    u32 r = (u + 0x7fffu + ((u >> 16) & 1u)) >> 16;   // RNE
    return (u16)r;
}

// ---------------------------------------------------------------------------
// W [512,256] fp32 -> WT [256,512] bf16 (transposed); also zeroes cursor[].
// ---------------------------------------------------------------------------
__global__ __launch_bounds__(256) void wcvt_zero(const float* __restrict__ W,
                                                 u16* __restrict__ WT,
                                                 int* __restrict__ cursor) {
    if (blockIdx.x < 2) {
        const int i = blockIdx.x * 256 + threadIdx.x;
        if (i < NBKT) cursor[i] = 0;
    }
    const int n  = threadIdx.x;
    const int k0 = blockIdx.x * 4;
    ushort4 o;
    o.x = f_to_bf(W[(size_t)(k0 + 0) * OUT_DIM + n]);
    o.y = f_to_bf(W[(size_t)(k0 + 1) * OUT_DIM + n]);
    o.z = f_to_bf(W[(size_t)(k0 + 2) * OUT_DIM + n]);
    o.w = f_to_bf(W[(size_t)(k0 + 3) * OUT_DIM + n]);
    *(ushort4*)(WT + (size_t)n * IN_DIM + k0) = o;
}

// ---------------------------------------------------------------------------
// FUSED heterogeneous kernel #2: blocks [0, NBKT) run scatter1 (edges ->
// bucket-major tmp, LDS atomics); blocks [NBKT, NBKT+782) run the round-8
// verified gemm.  Zero data dependency between roles (s1: er/ec/ev ->
// tmp+cursor; gemm: X,WT -> Sb; tmp and Sb are DISJOINT ws regions) and
// complementary pipes (LDS-atomic/latency vs MFMA/HBM).  Round-11 proved
// this overlap pattern works (fused s2+gemm = 80us ~ max of parts); s1
// (~79us serial) is the better blanket for gemm's 64.6us.
// LDS = 47.7KB union (s1's estage dominates) -> 3 blocks/CU, >= gemm's
// observed 1.6-3 blocks/CU residency, so the gemm role keeps its speed.
// ---------------------------------------------------------------------------
__global__ __launch_bounds__(256) void fused_s1_gemm(const int* __restrict__ er,
                                                     const int* __restrict__ ec,
                                                     const float* __restrict__ ev,
                                                     int* __restrict__ cursor,
                                                     int2* __restrict__ tmp,
                                                     const float* __restrict__ X,
                                                     const u16* __restrict__ WT,
                                                     u16* __restrict__ Sb) {
    __shared__ __align__(16) char smem[47712];

    const int t = threadIdx.x;

    if (blockIdx.x < NBKT) {
        // ---------------- scatter1 role (verbatim round-8 logic) ----------
        int2* estage = (int2*)smem;                     // [CHUNK]  32,768 B
        u16*  bslot  = (u16*)(smem + 32768);            // [CHUNK]   8,192 B
        int*  hcnt   = (int*)(smem + 40960);            // [NBKT]    1,564 B
        int*  loff   = (int*)(smem + 42524);            // [NBKT]    1,564 B
        int*  gbase  = (int*)(smem + 44088);            // [NBKT]    1,564 B
        int*  sc     = (int*)(smem + 45652);            // [512]     2,048 B

        const int base = blockIdx.x * CHUNK;
        const int nedge = min(CHUNK, N_EDGES - base);

        for (int k = t; k < NBKT; k += 256) hcnt[k] = 0;
        __syncthreads();

        int w0[EPT], w1[EPT], rk[EPT];
        #pragma unroll
        for (int j = 0; j < EPT; ++j) {
            const int i = j * 256 + t;            // coalesced per j
            rk[j] = -1;
            if (i < nedge) {
                const int e = base + i;
                const int r = er[e];
                const int bk = r >> 7;
                w0[j] = ec[e] | ((r & 127) << 16) | (bk << 23);
                w1[j] = __float_as_int(ev[e]);
                rk[j] = atomicAdd(&hcnt[bk], 1);
            }
        }
        __syncthreads();

        sc[t]       = (t < NBKT) ? hcnt[t] : 0;
        sc[t + 256] = (t + 256 < NBKT) ? hcnt[t + 256] : 0;
        __syncthreads();
        #pragma unroll
        for (int off = 1; off < 512; off <<= 1) {
            const int a0 = (t >= off) ? sc[t - off] : 0;
            const int a1 = sc[t + 256 - off];
            __syncthreads();
            sc[t] += a0;
            sc[t + 256] += a1;
            __syncthreads();
        }
        if (t < NBKT)       loff[t]       = sc[t] - hcnt[t];
        if (t + 256 < NBKT) loff[t + 256] = sc[t + 256] - hcnt[t + 256];

        if (t < NBKT && hcnt[t] > 0)
            gbase[t] = t * CAP + atomicAdd(&cursor[t], hcnt[t]);
        if (t + 256 < NBKT && hcnt[t + 256] > 0)
            gbase[t + 256] = (t + 256) * CAP + atomicAdd(&cursor[t + 256], hcnt[t + 256]);
        __syncthreads();

        #pragma unroll
        for (int j = 0; j < EPT; ++j) {
            if (rk[j] >= 0) {
                const int bk = ((u32)w0[j]) >> 23;
                const int s = loff[bk] + rk[j];
                estage[s] = make_int2(w0[j], w1[j]);
                bslot[s]  = (u16)bk;
            }
        }
        __syncthreads();

        for (int s = t; s < nedge; s += 256) {
            const int bk = bslot[s];
            const int2 e2 = estage[s];
            const int gpos = gbase[bk] + (s - loff[bk]);
            if (gpos < (bk + 1) * CAP)            // overflow guard (never in practice)
                tmp[gpos] = e2;
        }
    } else {
        // ---------------- gemm role (verbatim round-8 logic, 64.6us) ------
        u16* As = (u16*)smem;                    // [BM][LDA]  5,120 B
        u16* Bs = (u16*)(smem + BM * LDA * 2);   // [BN][LDA] 20,480 B

        const int wave = t >> 6;
        const int lane = t & 63;
        const int r0   = (blockIdx.x - NBKT) * BM;
        const int wn   = wave * 64;
        const int l15  = lane & 15;
        const int quad = lane >> 4;

        f32x4 acc[4][4];
        #pragma unroll
        for (int i = 0; i < 4; ++i)
            #pragma unroll
            for (int j = 0; j < 4; ++j) acc[i][j] = (f32x4)0.f;

        const int arow = t >> 2;
        const int akp  = (t & 3) * 8;
        const int xrow = min(r0 + arow, N_NODES - 1);
        const float* xsrc = X + (size_t)xrow * IN_DIM + akp;
        const int brow = t >> 1;
        const int bkp  = (t & 1) * 16;
        const u16* bsrc  = WT + (size_t)brow * IN_DIM + bkp;
        const u16* bsrc2 = bsrc + (size_t)128 * IN_DIM;

        float4 fA0 = *(const float4*)(xsrc + 0);
        float4 fA1 = *(const float4*)(xsrc + 4);
        uint4  rB0 = *(const uint4*)(bsrc + 0);
        uint4  rB1 = *(const uint4*)(bsrc + 8);
        uint4  rB2 = *(const uint4*)(bsrc2 + 0);
        uint4  rB3 = *(const uint4*)(bsrc2 + 8);

        for (int kc = 0; kc < IN_DIM; kc += BK) {
            {
                ushort4 p0, p1;
                p0.x = f_to_bf(fA0.x); p0.y = f_to_bf(fA0.y); p0.z = f_to_bf(fA0.z); p0.w = f_to_bf(fA0.w);
                p1.x = f_to_bf(fA1.x); p1.y = f_to_bf(fA1.y); p1.z = f_to_bf(fA1.z); p1.w = f_to_bf(fA1.w);
                *(ushort4*)&As[arow * LDA + akp + 0] = p0;
                *(ushort4*)&As[arow * LDA + akp + 4] = p1;
                *(uint4*)&Bs[brow * LDA + bkp + 0] = rB0;
                *(uint4*)&Bs[brow * LDA + bkp + 8] = rB1;
                *(uint4*)&Bs[(brow + 128) * LDA + bkp + 0] = rB2;
                *(uint4*)&Bs[(brow + 128) * LDA + bkp + 8] = rB3;
            }
            __syncthreads();

            if (kc + BK < IN_DIM) {
                fA0 = *(const float4*)(xsrc + kc + BK + 0);
                fA1 = *(const float4*)(xsrc + kc + BK + 4);
                rB0 = *(const uint4*)(bsrc + kc + BK + 0);
                rB1 = *(const uint4*)(bsrc + kc + BK + 8);
                rB2 = *(const uint4*)(bsrc2 + kc + BK + 0);
                rB3 = *(const uint4*)(bsrc2 + kc + BK + 8);
            }

            bf16x8 af[4], bfr[4];
            #pragma unroll
            for (int mt = 0; mt < 4; ++mt)
                af[mt] = *(const bf16x8*)&As[(mt * 16 + l15) * LDA + quad * 8];
            #pragma unroll
            for (int nt = 0; nt < 4; ++nt)
                bfr[nt] = *(const bf16x8*)&Bs[(wn + nt * 16 + l15) * LDA + quad * 8];
            #pragma unroll
            for (int mt = 0; mt < 4; ++mt)
                #pragma unroll
                for (int nt = 0; nt < 4; ++nt)
                    acc[mt][nt] = __builtin_amdgcn_mfma_f32_16x16x32_bf16(
                        af[mt], bfr[nt], acc[mt][nt], 0, 0, 0);
            __syncthreads();
        }

        #pragma unroll
        for (int mt = 0; mt < 4; ++mt) {
            #pragma unroll
            for (int r = 0; r < 4; ++r) {
                const int grow = r0 + mt * 16 + quad * 4 + r;
                if (grow < N_NODES) {
                    u16* dst = Sb + (size_t)grow * OUT_DIM + wn + l15;
                    #pragma unroll
                    for (int nt = 0; nt < 4; ++nt)
                        dst[nt * 16] = f_to_bf(acc[mt][nt][r]);
                }
            }
        }
    }
}

// ---------------------------------------------------------------------------
// scatter2: per bucket, inline 391-scan of bucket counts, LDS row-hist +
// scan -> row_ptr, scatter into 32KB L2-resident window (round-8 verified).
// ---------------------------------------------------------------------------
__global__ __launch_bounds__(256) void scatter2(const int* __restrict__ cursor,
                                                const int2* __restrict__ tmp,
                                                int* __restrict__ row_ptr,
                                                int2* __restrict__ sedge) {
    __shared__ int sc[512];
    __shared__ int orig[512];
    __shared__ int rcnt[RPB];
    __shared__ int rsc[RPB];
    __shared__ int rcur[RPB];
    const int t = threadIdx.x;
    const int b = blockIdx.x;

    const int c0 = (t < NBKT) ? min(cursor[t], CAP) : 0;
    const int c1 = (t + 256 < NBKT) ? min(cursor[t + 256], CAP) : 0;
    sc[t] = c0;       orig[t] = c0;
    sc[t + 256] = c1; orig[t + 256] = c1;
    __syncthreads();
    #pragma unroll
    for (int off = 1; off < 512; off <<= 1) {
        const int a0 = (t >= off) ? sc[t - off] : 0;
        const int a1 = sc[t + 256 - off];
        __syncthreads();
        sc[t] += a0;
        sc[t + 256] += a1;
        __syncthreads();
    }
    const int gb = sc[b] - orig[b];           // exclusive prefix at bucket b
    const int n  = orig[b];                   // this bucket's edge count
    const int2* src = tmp + (size_t)b * CAP;

    if (b == 0 && t == 0) row_ptr[N_NODES] = N_EDGES;

    if (t < RPB) rcnt[t] = 0;
    __syncthreads();
    for (int i = t; i < n; i += 256)
        atomicAdd(&rcnt[(((u32)src[i].x) >> 16) & 127], 1);
    __syncthreads();

    if (t < RPB) rsc[t] = rcnt[t];
    __syncthreads();
    #pragma unroll
    for (int off = 1; off < RPB; off <<= 1) {
        int a = 0;
        if (t < RPB && t >= off) a = rsc[t - off];
        __syncthreads();
        if (t < RPB) rsc[t] += a;
        __syncthreads();
    }
    if (t < RPB) {
        const int excl = rsc[t] - rcnt[t];
        rcur[t] = gb + excl;
        const int row = b * RPB + t;
        if (row < N_NODES) row_ptr[row] = gb + excl;
    }
    __syncthreads();

    for (int i = t; i < n; i += 256) {
        const int2 e2 = src[i];                       // L2-hot (2nd pass)
        const int rloc = (((u32)e2.x) >> 16) & 127;
        const int pos = atomicAdd(&rcur[rloc], 1);    // LDS atomic
        sedge[pos] = make_int2(e2.x & 0xFFFF, e2.y);  // within 32KB window
    }
}

// ---------------------------------------------------------------------------
// out[r] = bias + sum_{e in row r} val[e] * Sb[col[e]]  (round-7 verified,
// 114.5us; unsplit again -- decomposition phase over, one launch + one gap
// cheaper than two).
// ---------------------------------------------------------------------------
__global__ __launch_bounds__(256) void csr_spmm(const int* __restrict__ row_ptr,
                                                const int2* __restrict__ sedge,
                                                const u16* __restrict__ Sb,
                                                const float* __restrict__ bias,
                                                float* __restrict__ out) {
    const int wave = threadIdx.x >> 6;
    const int lane = threadIdx.x & 63;
    const int r = blockIdx.x * 4 + wave;
    if (r >= N_NODES) return;

    const int start = row_ptr[r];
    const int end   = row_ptr[r + 1];

    float4 acc = *(const float4*)(bias + lane * 4);
    const u16* sbase = Sb + lane * 4;

    int e = start;
    for (; e + 16 <= end; e += 16) {
        int2 ed[16];
        #pragma unroll
        for (int j = 0; j < 16; ++j) ed[j] = sedge[e + j];

        ushort4 sv[16];
        #pragma unroll
        for (int j = 0; j < 16; ++j)
            sv[j] = *(const ushort4*)(sbase + (size_t)ed[j].x * OUT_DIM);

        #pragma unroll
        for (int j = 0; j < 16; ++j) {
            const float vj = __int_as_float(ed[j].y);
            acc.x += vj * bf_to_f(sv[j].x);
            acc.y += vj * bf_to_f(sv[j].y);
            acc.z += vj * bf_to_f(sv[j].z);
            acc.w += vj * bf_to_f(sv[j].w);
        }
    }
    if (e < end) {
        int2 ed[16];
        #pragma unroll
        for (int j = 0; j < 16; ++j)
            ed[j] = sedge[min(e + j, end - 1)];
        #pragma unroll
        for (int j = 0; j < 16; ++j)
            if (e + j >= end) ed[j].y = 0;            // 0.0f bits on padding

        ushort4 sv[16];
        #pragma unroll
        for (int j = 0; j < 16; ++j)
            sv[j] = *(const ushort4*)(sbase + (size_t)ed[j].x * OUT_DIM);

        #pragma unroll
        for (int j = 0; j < 16; ++j) {
            const float vj = __int_as_float(ed[j].y);
            acc.x += vj * bf_to_f(sv[j].x);
            acc.y += vj * bf_to_f(sv[j].y);
            acc.z += vj * bf_to_f(sv[j].z);
            acc.w += vj * bf_to_f(sv[j].w);
        }
    }

    *(float4*)(out + (size_t)r * OUT_DIM + lane * 4) = acc;
}

extern "C" void kernel_launch(void* const* d_in, const int* in_sizes, int n_in,
                              void* d_out, int out_size, void* d_ws, size_t ws_size,
                              hipStream_t stream) {
    const float* X    = (const float*)d_in[0];
    const int*   er   = (const int*)d_in[1];
    const int*   ec   = (const int*)d_in[2];
    const float* ev   = (const float*)d_in[3];
    const float* W    = (const float*)d_in[4];
    const float* bias = (const float*)d_in[5];
    float* out        = (float*)d_out;

    // ws layout (~55 MB).  tmp must NOT alias Sb: in the fused kernel the
    // s1 role writes tmp concurrently with the gemm role writing Sb.
    char* ws = (char*)d_ws;
    u16*  Sb      = (u16*) (ws);                       // 25,600,000 B
    int2* sedge   = (int2*)(ws + 25600000);            // 12,800,000 B
    int2* tmp     = (int2*)(ws + 38400000);            // 16,015,360 B
    u16*  WT      = (u16*) (ws + 54415360);            //    262,144 B
    int*  row_ptr = (int*) (ws + 54677504);            //    200,004 B
    int*  cursor  = (int*) (ws + 54877508);            //      1,564 B

    hipLaunchKernelGGL(wcvt_zero, dim3(IN_DIM / 4), dim3(256), 0, stream,
                       W, WT, cursor);
    hipLaunchKernelGGL(fused_s1_gemm, dim3(NBKT + (N_NODES + BM - 1) / BM),
                       dim3(256), 0, stream,
                       er, ec, ev, cursor, tmp, X, WT, Sb);
    hipLaunchKernelGGL(scatter2, dim3(NBKT), dim3(256), 0, stream,
                       cursor, tmp, row_ptr, sedge);
    hipLaunchKernelGGL(csr_spmm, dim3((N_NODES + 3) / 4), dim3(256), 0, stream,
                       row_ptr, sedge, Sb, bias, out);
}